// Round 3
// baseline (300.625 us; speedup 1.0000x reference)
//
#include <hip/hip_runtime.h>
#include <hip/hip_bf16.h>

// Router: r[b,e] = || weights[e] @ x[b] ||_2
//   x: [8192, 4096] f32, weights: [16, 64, 4096] f32 -> out: [8192, 16] f32
//
// Round-3: cvt kernels unchanged (R2-verified).  GEMM rebuilt as a 3-buffer
// counted-vmcnt pipeline (T3+T4): BM=256 BN=128 BK=64, 512 thr (8 waves
// 4Mx2N, 64x64/wave = one expert), LDS 144 KiB, vmcnt(12) steady-state
// (never drains in main loop), raw s_barrier, setprio(1) around MFMA.
// R1/R2-verified XOR swizzle (both-sides) and C/D layout kept unchanged.

constexpr int Bdim = 8192;
constexpr int Ddim = 4096;
constexpr int Edim = 16;
constexpr int Ndim = 1024;

constexpr int BM = 256, BN = 128, BK = 64;
constexpr int NT  = Ddim / BK;        // 64 K-tiles
constexpr int ASZ = BM * BK * 2;      // 32 KiB per A buffer
constexpr int BSZ = BN * BK * 2;      // 16 KiB per B buffer

typedef __bf16 v8bf __attribute__((ext_vector_type(8)));
typedef float  v4f  __attribute__((ext_vector_type(4)));

// ---------------------------------------------------------------------------
// f32 -> bf16 RNE, pure integer.  uint4 load (16B) -> uint2 store (8B).
// ---------------------------------------------------------------------------
__device__ __forceinline__ unsigned rne2(unsigned lo, unsigned hi) {
  unsigned a = (lo + 0x7fffu + ((lo >> 16) & 1u)) >> 16;
  unsigned b = (hi + 0x7fffu + ((hi >> 16) & 1u)) & 0xffff0000u;
  return a | b;
}

__global__ void cvt_bf16(const uint4* __restrict__ in, uint2* __restrict__ out,
                         int n4) {
  int i = blockIdx.x * blockDim.x + threadIdx.x;
  int stride = gridDim.x * blockDim.x;
#pragma unroll 2
  for (; i < n4; i += stride) {
    uint4 v = in[i];
    uint2 r;
    r.x = rne2(v.x, v.y);
    r.y = rne2(v.z, v.w);
    out[i] = r;
  }
}

// ---------------------------------------------------------------------------
// async global->LDS, 16B per lane; LDS dest is wave-uniform base + lane*16.
// ---------------------------------------------------------------------------
__device__ __forceinline__ void gload_lds16(const void* gsrc, void* ldst) {
  __builtin_amdgcn_global_load_lds(
      (const __attribute__((address_space(1))) unsigned int*)gsrc,
      (__attribute__((address_space(3))) unsigned int*)ldst, 16, 0, 0);
}

// ---------------------------------------------------------------------------
// GEMM + fused router epilogue, 3-deep counted-vmcnt pipeline.
//
// Per-wave vmcnt ledger (6 wave-loads per tile, in-order retirement):
//   prologue: stage tiles 0,1,2            -> 18 outstanding
//   iter t:   wait vmcnt(12)  => tile t landed (t+1,t+2 in flight)
//             barrier; compute buf[t%3]; lgkmcnt(0); barrier
//             stage tile t+3 into buf[t%3] -> back to 18
//   tail:     t=62 waits 6, t=63 waits 0.
// ---------------------------------------------------------------------------
__global__ __launch_bounds__(512, 2)
void gemm_router(const __bf16* __restrict__ Xp,  // [8192][4096]
                 const __bf16* __restrict__ Wp,  // [1024][4096]
                 float* __restrict__ out) {      // [8192][16]
  __shared__ __align__(16) char As[3 * ASZ];  // 96 KiB
  __shared__ __align__(16) char Bs[3 * BSZ];  // 48 KiB

  const int bid = blockIdx.x;       // 256 blocks: bn fastest -> XCD = bn
  const int bm  = bid >> 3;         // 0..31
  const int bn  = bid & 7;          // 0..7
  const int tid  = threadIdx.x;
  const int lane = tid & 63;
  const int wid  = tid >> 6;        // 0..7
  const int wr   = wid >> 1;        // wave row 0..3 -> 64-row strip
  const int wc   = wid & 1;         // wave col 0..1 -> 64 cols = 1 expert
  const int l15  = lane & 15;
  const int lg   = lane >> 4;
  const int lr   = lane >> 3;       // 0..7 (row within 8-row chunk)
  const int ss   = (lane & 7) ^ lr; // pre-swizzled source 16B-slot

  // staging addresses: A = 32 chunks of 8 rows (4/wave), B = 16 chunks (2/wave)
  const __bf16* gA[4]; char* dA[4];
#pragma unroll
  for (int c = 0; c < 4; ++c) {
    int row = wid * 32 + c * 8 + lr;
    gA[c] = Xp + (size_t)(bm * BM + row) * Ddim + ss * 8;
    dA[c] = As + (wid * 4 + c) * 1024;
  }
  const __bf16* gB[2]; char* dB[2];
#pragma unroll
  for (int c = 0; c < 2; ++c) {
    int row = wid * 16 + c * 8 + lr;
    gB[c] = Wp + (size_t)(bn * BN + row) * Ddim + ss * 8;
    dB[c] = Bs + (wid * 2 + c) * 1024;
  }

  auto STAGE = [&](int kt, int buf) {
    const int ko = kt * BK;
#pragma unroll
    for (int c = 0; c < 4; ++c) gload_lds16(gA[c] + ko, dA[c] + buf * ASZ);
#pragma unroll
    for (int c = 0; c < 2; ++c) gload_lds16(gB[c] + ko, dB[c] + buf * BSZ);
  };

  v4f acc[4][4] = {};

  STAGE(0, 0);
  STAGE(1, 1);
  STAGE(2, 2);

  int cur = 0;
  for (int t = 0; t < NT; ++t) {
    if (t < NT - 2)       asm volatile("s_waitcnt vmcnt(12)" ::: "memory");
    else if (t == NT - 2) asm volatile("s_waitcnt vmcnt(6)"  ::: "memory");
    else                  asm volatile("s_waitcnt vmcnt(0)"  ::: "memory");
    __builtin_amdgcn_s_barrier();
    __builtin_amdgcn_sched_barrier(0);

    const char* Ab = As + cur * ASZ;
    const char* Bb = Bs + cur * BSZ;
#pragma unroll
    for (int kk = 0; kk < 2; ++kk) {
      const int sb = (kk << 2) + lg;     // 16B-slot index before swizzle
      v8bf a[4], b[4];
#pragma unroll
      for (int mf = 0; mf < 4; ++mf) {
        int row = (wr << 6) + (mf << 4) + l15;
        a[mf] = *(const v8bf*)(Ab + row * 128 + ((sb ^ (l15 & 7)) << 4));
      }
#pragma unroll
      for (int nf = 0; nf < 4; ++nf) {
        int col = (wc << 6) + (nf << 4) + l15;
        b[nf] = *(const v8bf*)(Bb + col * 128 + ((sb ^ (l15 & 7)) << 4));
      }
      __builtin_amdgcn_s_setprio(1);
#pragma unroll
      for (int mf = 0; mf < 4; ++mf)
#pragma unroll
        for (int nf = 0; nf < 4; ++nf)
          acc[mf][nf] = __builtin_amdgcn_mfma_f32_16x16x32_bf16(
              a[mf], b[nf], acc[mf][nf], 0, 0, 0);
      __builtin_amdgcn_s_setprio(0);
    }

    asm volatile("s_waitcnt lgkmcnt(0)" ::: "memory");
    __builtin_amdgcn_s_barrier();
    __builtin_amdgcn_sched_barrier(0);
    if (t < NT - 3) STAGE(t + 3, cur);
    cur = (cur == 2) ? 0 : cur + 1;
  }

  // --- fused epilogue: r[row, e] = sqrt( sum_{k<64} C[row, e*64+k]^2 ) ---
  // C/D layout (m89/m91): col = lane&15, row = (lane>>4)*4 + reg.
  const int e = (bn << 1) + wc;
#pragma unroll
  for (int mf = 0; mf < 4; ++mf) {
#pragma unroll
    for (int reg = 0; reg < 4; ++reg) {
      float t = 0.f;
#pragma unroll
      for (int nf = 0; nf < 4; ++nf) {
        float v = acc[mf][nf][reg];
        t = fmaf(v, v, t);
      }
      t += __shfl_xor(t, 1);
      t += __shfl_xor(t, 2);
      t += __shfl_xor(t, 4);
      t += __shfl_xor(t, 8);
      if (l15 == 0) {
        int row = (bm << 8) + (wr << 6) + (mf << 4) + (lg << 2) + reg;
        out[(size_t)row * Edim + e] = sqrtf(t);
      }
    }
  }
}

// ---------------------------------------------------------------------------
// Fallback (ws too small): plain fp32, correct but slow.
// ---------------------------------------------------------------------------
__global__ void router_naive(const float* __restrict__ x,
                             const float* __restrict__ w,
                             float* __restrict__ out) {
  int b = blockIdx.x;
  __shared__ float xs[Ddim];
  for (int d = threadIdx.x; d < Ddim; d += 256) xs[d] = x[(size_t)b * Ddim + d];
  __syncthreads();
  int n0 = threadIdx.x * 4;
  const float* wrow = w + (size_t)n0 * Ddim;
  float acc[4] = {0.f, 0.f, 0.f, 0.f};
  for (int d = 0; d < Ddim; ++d) {
    float xv = xs[d];
#pragma unroll
    for (int j = 0; j < 4; ++j) acc[j] = fmaf(xv, wrow[(size_t)j * Ddim + d], acc[j]);
  }
  float p = acc[0] * acc[0] + acc[1] * acc[1] + acc[2] * acc[2] + acc[3] * acc[3];
  p += __shfl_xor(p, 1);
  p += __shfl_xor(p, 2);
  p += __shfl_xor(p, 4);
  p += __shfl_xor(p, 8);
  if ((threadIdx.x & 15) == 0)
    out[(size_t)b * Edim + (threadIdx.x >> 4)] = sqrtf(p);
}

extern "C" void kernel_launch(void* const* d_in, const int* in_sizes, int n_in,
                              void* d_out, int out_size, void* d_ws,
                              size_t ws_size, hipStream_t stream) {
  const float* x = (const float*)d_in[0];
  const float* w = (const float*)d_in[1];
  float* out = (float*)d_out;

  const size_t xp_elems = (size_t)Bdim * Ddim;   // 33.5M bf16 (67 MB)
  const size_t wp_elems = (size_t)Ndim * Ddim;   // 4.2M bf16 (8.4 MB)
  const size_t need = (xp_elems + wp_elems) * sizeof(__bf16);  // ~76 MB

  if (ws_size >= need) {
    __bf16* Xp = (__bf16*)d_ws;
    __bf16* Wp = Xp + xp_elems;
    cvt_bf16<<<2048, 256, 0, stream>>>((const uint4*)x, (uint2*)Xp,
                                       Bdim * Ddim / 4);
    cvt_bf16<<<512, 256, 0, stream>>>((const uint4*)w, (uint2*)Wp,
                                      Ndim * Ddim / 4);
    gemm_router<<<(Bdim / BM) * (Ndim / BN), 512, 0, stream>>>(Xp, Wp, out);
  } else {
    router_naive<<<Bdim, 256, 0, stream>>>(x, w, out);
  }
}

// Round 5
// 290.501 us; speedup vs baseline: 1.0349x; 1.0349x over previous
//
#include <hip/hip_runtime.h>
#include <hip/hip_bf16.h>

// Router: r[b,e] = || weights[e] @ x[b] ||_2
//   x: [8192, 4096] f32, weights: [16, 64, 4096] f32 -> out: [8192, 16] f32
//
// Round-5 = Round-4 fine-phase pipeline + two correctness fixes:
//  (a) prologue vmcnt(6)+barrier  (R4's NaN: tile-0 ds_reads raced the
//      un-waited prologue DMA — no vmcnt existed before first compute);
//  (b) trailing s_barrier after each phase's MFMA (m201 template): makes
//      the stage-into-old-buffer W-A-R architecturally safe (every wave's
//      lgkmcnt(0) read-drain precedes its MFMA precedes the barrier,
//      which precedes any wave's clobbering DMA issue).
// Structure: BM=256 BN=128 BK=64, 8 waves 4Mx2N (wave 64x64 = 1 expert),
// 3 LDS buffers (144 KiB), 2 phases/K-tile, steady-state vmcnt(6) (never
// drains until the tail).  Swizzle (both-sides) + C/D epilogue unchanged.

constexpr int Bdim = 8192;
constexpr int Ddim = 4096;
constexpr int Edim = 16;
constexpr int Ndim = 1024;

constexpr int BM = 256, BN = 128, BK = 64;
constexpr int NT  = Ddim / BK;        // 64 K-tiles
constexpr int ASZ = BM * BK * 2;      // 32 KiB per A buffer
constexpr int BSZ = BN * BK * 2;      // 16 KiB per B buffer

typedef __bf16 v8bf __attribute__((ext_vector_type(8)));
typedef float  v4f  __attribute__((ext_vector_type(4)));

// ---------------------------------------------------------------------------
// f32 -> bf16 RNE, pure integer.  uint4 load (16B) -> uint2 store (8B).
// ---------------------------------------------------------------------------
__device__ __forceinline__ unsigned rne2(unsigned lo, unsigned hi) {
  unsigned a = (lo + 0x7fffu + ((lo >> 16) & 1u)) >> 16;
  unsigned b = (hi + 0x7fffu + ((hi >> 16) & 1u)) & 0xffff0000u;
  return a | b;
}

__global__ void cvt_bf16(const uint4* __restrict__ in, uint2* __restrict__ out,
                         int n4) {
  int i = blockIdx.x * blockDim.x + threadIdx.x;
  int stride = gridDim.x * blockDim.x;
#pragma unroll 2
  for (; i < n4; i += stride) {
    uint4 v = in[i];
    uint2 r;
    r.x = rne2(v.x, v.y);
    r.y = rne2(v.z, v.w);
    out[i] = r;
  }
}

// ---------------------------------------------------------------------------
// async global->LDS, 16B per lane; LDS dest is wave-uniform base + lane*16.
// ---------------------------------------------------------------------------
__device__ __forceinline__ void gload_lds16(const void* gsrc, void* ldst) {
  __builtin_amdgcn_global_load_lds(
      (const __attribute__((address_space(1))) unsigned int*)gsrc,
      (__attribute__((address_space(3))) unsigned int*)ldst, 16, 0, 0);
}

// ---------------------------------------------------------------------------
// GEMM + fused router epilogue, fine-phase 3-buffer pipeline.
//
// vmcnt ledger (6 loads/tile/wave, in-order retirement):
//   prologue: stage tiles 0,1 (12 out); vmcnt(6) -> tile 0 landed; barrier.
//   iter t:  ph1 {ds_read(t); stage half1(t+2); barrier; lgkm0; MFMA; barrier}
//            ph2 {ds_read(t); stage half2(t+2); vmcnt(6) [tile t+1 landed,
//                 t+2 in flight]; barrier; lgkm0; MFMA; barrier}
//   tail:    t=NT-2 -> vmcnt(0); t=NT-1 -> no wait, no stage.
// ---------------------------------------------------------------------------
__global__ __launch_bounds__(512, 2)
void gemm_router(const __bf16* __restrict__ Xp,  // [8192][4096]
                 const __bf16* __restrict__ Wp,  // [1024][4096]
                 float* __restrict__ out) {      // [8192][16]
  __shared__ __align__(16) char As[3 * ASZ];  // 96 KiB
  __shared__ __align__(16) char Bs[3 * BSZ];  // 48 KiB

  const int bid = blockIdx.x;       // 256 blocks: bn fastest -> XCD locality
  const int bm  = bid >> 3;         // 0..31
  const int bn  = bid & 7;          // 0..7
  const int tid  = threadIdx.x;
  const int lane = tid & 63;
  const int wid  = tid >> 6;        // 0..7
  const int wr   = wid >> 1;        // wave row 0..3 -> 64-row strip
  const int wc   = wid & 1;         // wave col 0..1 -> 64 cols = 1 expert
  const int l15  = lane & 15;
  const int lg   = lane >> 4;
  const int lr   = lane >> 3;       // row within 8-row chunk
  const int ss   = (lane & 7) ^ lr; // pre-swizzled source 16B-slot
  const int l7   = l15 & 7;

  // staging addresses: A = 32 chunks of 8 rows (4/wave), B = 16 chunks (2/wave)
  const __bf16* gA[4]; char* dA[4];
#pragma unroll
  for (int c = 0; c < 4; ++c) {
    int row = wid * 32 + c * 8 + lr;
    gA[c] = Xp + (size_t)(bm * BM + row) * Ddim + ss * 8;
    dA[c] = As + (wid * 4 + c) * 1024;
  }
  const __bf16* gB[2]; char* dB[2];
#pragma unroll
  for (int c = 0; c < 2; ++c) {
    int row = wid * 16 + c * 8 + lr;
    gB[c] = Wp + (size_t)(bn * BN + row) * Ddim + ss * 8;
    dB[c] = Bs + (wid * 2 + c) * 1024;
  }

  v4f acc[4][4] = {};

  // prologue: tiles 0 and 1, full; then ensure tile 0 landed (R4 fix a)
#pragma unroll
  for (int c = 0; c < 4; ++c) gload_lds16(gA[c], dA[c]);
#pragma unroll
  for (int c = 0; c < 2; ++c) gload_lds16(gB[c], dB[c]);
#pragma unroll
  for (int c = 0; c < 4; ++c) gload_lds16(gA[c] + BK, dA[c] + ASZ);
#pragma unroll
  for (int c = 0; c < 2; ++c) gload_lds16(gB[c] + BK, dB[c] + BSZ);
  asm volatile("s_waitcnt vmcnt(6)" ::: "memory");
  __builtin_amdgcn_s_barrier();
  __builtin_amdgcn_sched_barrier(0);

  int cur = 0;
  for (int t = 0; t < NT; ++t) {
    const char* Ab = As + cur * ASZ;
    const char* Bb = Bs + cur * BSZ;
    int nxt = cur + 2; if (nxt >= 3) nxt -= 3;   // buffer for tile t+2
    const bool st = (t + 2 < NT);
    const int ko = (t + 2) * BK;

    // ================= phase 1: kk = 0 =================
    v8bf a0[4], b0[4];
#pragma unroll
    for (int mf = 0; mf < 4; ++mf) {
      int row = (wr << 6) + (mf << 4) + l15;
      a0[mf] = *(const v8bf*)(Ab + row * 128 + ((lg ^ l7) << 4));
    }
#pragma unroll
    for (int nf = 0; nf < 4; ++nf) {
      int col = (wc << 6) + (nf << 4) + l15;
      b0[nf] = *(const v8bf*)(Bb + col * 128 + ((lg ^ l7) << 4));
    }
    if (st) {  // half 1 of tile t+2: A chunks 0,1 + B chunk 0
      gload_lds16(gA[0] + ko, dA[0] + nxt * ASZ);
      gload_lds16(gA[1] + ko, dA[1] + nxt * ASZ);
      gload_lds16(gB[0] + ko, dB[0] + nxt * BSZ);
    }
    __builtin_amdgcn_s_barrier();
    asm volatile("s_waitcnt lgkmcnt(0)" ::: "memory");
    __builtin_amdgcn_sched_barrier(0);
    __builtin_amdgcn_s_setprio(1);
#pragma unroll
    for (int mf = 0; mf < 4; ++mf)
#pragma unroll
      for (int nf = 0; nf < 4; ++nf)
        acc[mf][nf] = __builtin_amdgcn_mfma_f32_16x16x32_bf16(
            a0[mf], b0[nf], acc[mf][nf], 0, 0, 0);
    __builtin_amdgcn_s_setprio(0);
    __builtin_amdgcn_s_barrier();          // (fix b) read-drain before clobber

    // ================= phase 2: kk = 1 =================
    v8bf a1[4], b1[4];
#pragma unroll
    for (int mf = 0; mf < 4; ++mf) {
      int row = (wr << 6) + (mf << 4) + l15;
      a1[mf] = *(const v8bf*)(Ab + row * 128 + (((4 + lg) ^ l7) << 4));
    }
#pragma unroll
    for (int nf = 0; nf < 4; ++nf) {
      int col = (wc << 6) + (nf << 4) + l15;
      b1[nf] = *(const v8bf*)(Bb + col * 128 + (((4 + lg) ^ l7) << 4));
    }
    if (st) {  // half 2 of tile t+2: A chunks 2,3 + B chunk 1
      gload_lds16(gA[2] + ko, dA[2] + nxt * ASZ);
      gload_lds16(gA[3] + ko, dA[3] + nxt * ASZ);
      gload_lds16(gB[1] + ko, dB[1] + nxt * BSZ);
    }
    if (t < NT - 2)       asm volatile("s_waitcnt vmcnt(6)" ::: "memory");
    else if (t == NT - 2) asm volatile("s_waitcnt vmcnt(0)" ::: "memory");
    __builtin_amdgcn_s_barrier();
    asm volatile("s_waitcnt lgkmcnt(0)" ::: "memory");
    __builtin_amdgcn_sched_barrier(0);
    __builtin_amdgcn_s_setprio(1);
#pragma unroll
    for (int mf = 0; mf < 4; ++mf)
#pragma unroll
      for (int nf = 0; nf < 4; ++nf)
        acc[mf][nf] = __builtin_amdgcn_mfma_f32_16x16x32_bf16(
            a1[mf], b1[nf], acc[mf][nf], 0, 0, 0);
    __builtin_amdgcn_s_setprio(0);
    __builtin_amdgcn_s_barrier();          // (fix b)

    cur += 1; if (cur >= 3) cur -= 3;
  }

  // --- fused epilogue: r[row, e] = sqrt( sum_{k<64} C[row, e*64+k]^2 ) ---
  // C/D layout (m89/m91): col = lane&15, row = (lane>>4)*4 + reg.
  const int e = (bn << 1) + wc;
#pragma unroll
  for (int mf = 0; mf < 4; ++mf) {
#pragma unroll
    for (int reg = 0; reg < 4; ++reg) {
      float t = 0.f;
#pragma unroll
      for (int nf = 0; nf < 4; ++nf) {
        float v = acc[mf][nf][reg];
        t = fmaf(v, v, t);
      }
      t += __shfl_xor(t, 1);
      t += __shfl_xor(t, 2);
      t += __shfl_xor(t, 4);
      t += __shfl_xor(t, 8);
      if (l15 == 0) {
        int row = (bm << 8) + (wr << 6) + (mf << 4) + (lg << 2) + reg;
        out[(size_t)row * Edim + e] = sqrtf(t);
      }
    }
  }
}

// ---------------------------------------------------------------------------
// Fallback (ws too small): plain fp32, correct but slow.
// ---------------------------------------------------------------------------
__global__ void router_naive(const float* __restrict__ x,
                             const float* __restrict__ w,
                             float* __restrict__ out) {
  int b = blockIdx.x;
  __shared__ float xs[Ddim];
  for (int d = threadIdx.x; d < Ddim; d += 256) xs[d] = x[(size_t)b * Ddim + d];
  __syncthreads();
  int n0 = threadIdx.x * 4;
  const float* wrow = w + (size_t)n0 * Ddim;
  float acc[4] = {0.f, 0.f, 0.f, 0.f};
  for (int d = 0; d < Ddim; ++d) {
    float xv = xs[d];
#pragma unroll
    for (int j = 0; j < 4; ++j) acc[j] = fmaf(xv, wrow[(size_t)j * Ddim + d], acc[j]);
  }
  float p = acc[0] * acc[0] + acc[1] * acc[1] + acc[2] * acc[2] + acc[3] * acc[3];
  p += __shfl_xor(p, 1);
  p += __shfl_xor(p, 2);
  p += __shfl_xor(p, 4);
  p += __shfl_xor(p, 8);
  if ((threadIdx.x & 15) == 0)
    out[(size_t)b * Edim + (threadIdx.x >> 4)] = sqrtf(p);
}

extern "C" void kernel_launch(void* const* d_in, const int* in_sizes, int n_in,
                              void* d_out, int out_size, void* d_ws,
                              size_t ws_size, hipStream_t stream) {
  const float* x = (const float*)d_in[0];
  const float* w = (const float*)d_in[1];
  float* out = (float*)d_out;

  const size_t xp_elems = (size_t)Bdim * Ddim;   // 33.5M bf16 (67 MB)
  const size_t wp_elems = (size_t)Ndim * Ddim;   // 4.2M bf16 (8.4 MB)
  const size_t need = (xp_elems + wp_elems) * sizeof(__bf16);  // ~76 MB

  if (ws_size >= need) {
    __bf16* Xp = (__bf16*)d_ws;
    __bf16* Wp = Xp + xp_elems;
    cvt_bf16<<<2048, 256, 0, stream>>>((const uint4*)x, (uint2*)Xp,
                                       Bdim * Ddim / 4);
    cvt_bf16<<<512, 256, 0, stream>>>((const uint4*)w, (uint2*)Wp,
                                      Ndim * Ddim / 4);
    gemm_router<<<(Bdim / BM) * (Ndim / BN), 512, 0, stream>>>(Xp, Wp, out);
  } else {
    router_naive<<<Bdim, 256, 0, stream>>>(x, w, out);
  }
}